// Round 4
// baseline (145.499 us; speedup 1.0000x reference)
//
#include <hip/hip_runtime.h>
#include <math.h>

// TopKMoEGate: T = 16384 tokens, D = 1024, E = 64, topK = 2.
// Round 4: MFMA path. fp32 x,w are split EXACTLY into 3 bf16 slices
// (hi+mid+lo, Dekker-style; residuals exact in fp32). Six cross terms
// (hh | hm,mh | hl,mm,lh) via v_mfma_f32_16x16x32_bf16, hh in its own fp32
// accumulator -> logit error ~5e-7 (np-reference-level).
//  - Wave = 16 tokens x 64 experts (4 N-tiles): x read ONCE from HBM.
//  - NO LDS, NO barriers: A-frags loaded direct from x in frag order
//    (m=lane&15, k=quad*8+j), depth-2 register prefetch; B-frags from a
//    pre-sliced frag-ordered image in d_ws (384 KB, L2/L1-hot).
//  - Fused epilogue: C row=quad*4+reg (token), col=lane&15 (expert);
//    quad-local shfl_xor butterfly top-2 (jax tie-break), sparse softmax.
// Roofline: HBM 64 MB x + 4 MB noise + 4.3 MB out ~= 11 us; MFMA ~3 us.

#define DDIM 1024
#define NEXP 64
#define NTOK 16384

typedef float  f4 __attribute__((ext_vector_type(4)));
typedef short  s8 __attribute__((ext_vector_type(8)));

static __device__ __forceinline__ unsigned short f2bf(float f) {
    unsigned u = __float_as_uint(f);
    u += 0x7FFFu + ((u >> 16) & 1u);          // RNE
    return (unsigned short)(u >> 16);
}
static __device__ __forceinline__ float bf2f(unsigned short h) {
    return __uint_as_float(((unsigned)h) << 16);
}

// ---- kernel 0: slice gate_w into 3 bf16 levels, frag-ordered image ----
// unit16 U(c,kk,lv,e,q) = ((c*2+kk)*3+lv)*256 + e*4 + q ; holds w[e][k0..k0+7]
// with k0 = c*64 + kk*32 + q*8.  Total 24576 units * 16B = 384 KB.
__global__ __launch_bounds__(256)
void w_prep(const float* __restrict__ gw, unsigned short* __restrict__ wimg) {
    const int uid = blockIdx.x * 256 + threadIdx.x;   // 8192 threads
    const int c   = uid >> 9;
    const int kk  = (uid >> 8) & 1;
    const int e   = (uid >> 2) & 63;
    const int qq  = uid & 3;
    const int k0  = c * 64 + kk * 32 + qq * 8;
    const float* src = gw + (size_t)e * DDIM + k0;
    s8 hv, mv, lv;
    #pragma unroll
    for (int j = 0; j < 8; ++j) {
        const float f = src[j];
        const unsigned short h = f2bf(f);
        const float r1 = f - bf2f(h);
        const unsigned short m = f2bf(r1);
        const float r2 = r1 - bf2f(m);
        const unsigned short l = f2bf(r2);
        hv[j] = (short)h; mv[j] = (short)m; lv[j] = (short)l;
    }
    const size_t base = (size_t)((c * 2 + kk) * 3) * 256 + e * 4 + qq;
    *(s8*)(wimg + base * 8)         = hv;
    *(s8*)(wimg + (base + 256) * 8) = mv;
    *(s8*)(wimg + (base + 512) * 8) = lv;
}

// ---- kernel 1: MFMA GEMM + fused noisy top-2 + sparse softmax ----
static __device__ __forceinline__ bool bt(float av, int ai, float bv, int bi) {
    return av > bv || (av == bv && ai < bi);   // a ranks before b (jax top_k)
}

__global__ __launch_bounds__(256)
void moe_mfma(const float* __restrict__ x,
              const unsigned short* __restrict__ wimg,
              const float* __restrict__ nwt,
              const float* __restrict__ noise,
              float* __restrict__ out_w,
              float* __restrict__ out_i)
{
    const int lane = threadIdx.x & 63;
    const int m    = lane & 15;            // token-within-tile / expert col
    const int q    = lane >> 4;            // quad
    const int tokBase = blockIdx.x * 64 + (threadIdx.x >> 6) * 16;
    const float* xrow = x + (size_t)(tokBase + m) * DDIM + q * 8;

    f4 acc0[4], acc1[4];
    #pragma unroll
    for (int t = 0; t < 4; ++t) { acc0[t] = (f4)0.f; acc1[t] = (f4)0.f; }

    // fp32 staging, depth-2 prefetch (3 rotating slots, fully unrolled -> regs)
    f4 stage[3][4];
    #pragma unroll
    for (int p = 0; p < 2; ++p) {
        const float* s = xrow + p * 64;
        stage[p][0] = *(const f4*)(s);
        stage[p][1] = *(const f4*)(s + 4);
        stage[p][2] = *(const f4*)(s + 32);
        stage[p][3] = *(const f4*)(s + 36);
    }

    #pragma unroll
    for (int c = 0; c < 16; ++c) {
        if (c + 2 < 16) {
            const int slot = (c + 2) % 3;
            const float* s = xrow + (c + 2) * 64;
            stage[slot][0] = *(const f4*)(s);
            stage[slot][1] = *(const f4*)(s + 4);
            stage[slot][2] = *(const f4*)(s + 32);
            stage[slot][3] = *(const f4*)(s + 36);
        }
        // convert this chunk's 16 fp32 -> 3-level bf16 A-frags (2 kk)
        s8 ah[2], am[2], al[2];
        const float* sv = (const float*)stage[c % 3];
        #pragma unroll
        for (int kk = 0; kk < 2; ++kk) {
            #pragma unroll
            for (int j = 0; j < 8; ++j) {
                const float f = sv[kk * 8 + j];
                const unsigned short h = f2bf(f);
                const float r1 = f - bf2f(h);
                const unsigned short mm = f2bf(r1);
                const float r2 = r1 - bf2f(mm);
                ah[kk][j] = (short)h;
                am[kk][j] = (short)mm;
                al[kk][j] = (short)f2bf(r2);
            }
        }
        #pragma unroll
        for (int kk = 0; kk < 2; ++kk) {
            const unsigned short* bbase =
                wimg + ((size_t)((c * 2 + kk) * 3) * 256 + m * 4 + q) * 8;
            #pragma unroll
            for (int t = 0; t < 4; ++t) {
                const s8 bh = *(const s8*)(bbase + (size_t)t * 64 * 8);
                const s8 bm = *(const s8*)(bbase + (size_t)(256 + t * 64) * 8);
                const s8 bl = *(const s8*)(bbase + (size_t)(512 + t * 64) * 8);
                acc0[t] = __builtin_amdgcn_mfma_f32_16x16x32_bf16(ah[kk], bh, acc0[t], 0, 0, 0);
                acc1[t] = __builtin_amdgcn_mfma_f32_16x16x32_bf16(ah[kk], bm, acc1[t], 0, 0, 0);
                acc1[t] = __builtin_amdgcn_mfma_f32_16x16x32_bf16(am[kk], bh, acc1[t], 0, 0, 0);
                acc1[t] = __builtin_amdgcn_mfma_f32_16x16x32_bf16(ah[kk], bl, acc1[t], 0, 0, 0);
                acc1[t] = __builtin_amdgcn_mfma_f32_16x16x32_bf16(am[kk], bm, acc1[t], 0, 0, 0);
                acc1[t] = __builtin_amdgcn_mfma_f32_16x16x32_bf16(al[kk], bh, acc1[t], 0, 0, 0);
            }
        }
    }

    // fused epilogue
    float nw_[4];
    #pragma unroll
    for (int t = 0; t < 4; ++t) nw_[t] = nwt[m + 16 * t];

    #pragma unroll
    for (int r = 0; r < 4; ++r) {
        const int tok = tokBase + q * 4 + r;
        float lnv[4];
        #pragma unroll
        for (int t = 0; t < 4; ++t) {
            const int e = m + 16 * t;
            lnv[t] = acc0[t][r] + acc1[t][r]
                   + noise[(size_t)tok * NEXP + e] * nw_[t];
        }
        // local top-2 among this lane's 4 experts (e ascending)
        float v1 = lnv[0], v2 = -3.4e38f;
        int   i1 = m, i2 = -1;
        #pragma unroll
        for (int t = 1; t < 4; ++t) {
            const int e = m + 16 * t;
            if (lnv[t] > v1) { v2 = v1; i2 = i1; v1 = lnv[t]; i1 = e; }
            else if (lnv[t] > v2) { v2 = lnv[t]; i2 = e; }
        }
        // quad-local butterfly merge (offsets 1,2,4,8 stay within 16 lanes)
        #pragma unroll
        for (int off = 1; off < 16; off <<= 1) {
            const float pv1 = __shfl_xor(v1, off);
            const int   pi1 = __shfl_xor(i1, off);
            const float pv2 = __shfl_xor(v2, off);
            const int   pi2 = __shfl_xor(i2, off);
            if (bt(pv1, pi1, v1, i1)) {
                if (bt(v1, i1, pv2, pi2)) { v2 = v1; i2 = i1; }
                else                      { v2 = pv2; i2 = pi2; }
                v1 = pv1; i1 = pi1;
            } else if (bt(pv1, pi1, v2, i2)) {
                v2 = pv1; i2 = pi1;
            }
        }
        const float d   = expf(v2 - v1);
        const float inv = 1.f / (1.f + d);
        #pragma unroll
        for (int t = 0; t < 4; ++t) {
            const int e = m + 16 * t;
            const float w = (e == i1) ? inv : ((e == i2) ? d * inv : 0.f);
            out_w[(size_t)tok * NEXP + e] = w;
        }
        if (m == 0) {
            out_i[(size_t)tok * 2]     = (float)i1;
            out_i[(size_t)tok * 2 + 1] = (float)i2;
        }
    }
}

extern "C" void kernel_launch(void* const* d_in, const int* in_sizes, int n_in,
                              void* d_out, int out_size, void* d_ws, size_t ws_size,
                              hipStream_t stream) {
    const float* x     = (const float*)d_in[0];
    const float* gw    = (const float*)d_in[1];
    const float* nwt   = (const float*)d_in[2];
    const float* noise = (const float*)d_in[3];
    float* out_w = (float*)d_out;                        // [NTOK][64]
    float* out_i = (float*)d_out + (size_t)NTOK * NEXP;  // [NTOK][2] as float
    unsigned short* wimg = (unsigned short*)d_ws;        // 384 KB image

    hipLaunchKernelGGL(w_prep, dim3(32), dim3(256), 0, stream, gw, wimg);
    hipLaunchKernelGGL(moe_mfma, dim3(NTOK / 64), dim3(256), 0, stream,
                       x, wimg, nwt, noise, out_w, out_i);
}

// Round 5
// 122.967 us; speedup vs baseline: 1.1832x; 1.1832x over previous
//
#include <hip/hip_runtime.h>
#include <math.h>

// TopKMoEGate: T = 16384, D = 1024, E = 64, topK = 2.
// Round 5: MFMA 3-slice-bf16 path (round-4-verified numerics) + TLP fix.
//  - Round-4 failure mode: 16-tok waves x full E -> only 1024 waves = 1
//    wave/SIMD, zero latency hiding (MfmaUtil 7%, VALUBusy 10%).
//  - Split-K = 4: 1024 blocks = 4 blocks/CU = 16 waves/CU. Partials (16 MB)
//    in d_ws; reduce kernel (round-3-verified butterfly) does noise + top-2
//    + sparse softmax.
//  - B image pre-sliced AND pre-permuted to LDS lane order by w_prep;
//    staged per block per k64-chunk via global_load_lds width=16 (flat copy),
//    compute reads are stride-1 ds_read_b128 (2-way aliasing = free).
//  - Truncating 3-way bf16 split (h+m+l, rep err ~2^-24): fewer VALU ops.

#define DDIM 1024
#define NEXP 64
#define NTOK 16384
#define NSPLIT 4
#define CPB 4                 // k64-chunks per block (K range 256)

typedef float f4 __attribute__((ext_vector_type(4)));
typedef short s8 __attribute__((ext_vector_type(8)));
typedef unsigned int u32;

static __device__ __forceinline__ void split3(float f, short& h, short& m, short& l) {
    const u32 uf = __float_as_uint(f);
    h = (short)(uf >> 16);
    const float r1 = f - __uint_as_float(uf & 0xffff0000u);
    const u32 u1 = __float_as_uint(r1);
    m = (short)(u1 >> 16);
    const float r2 = r1 - __uint_as_float(u1 & 0xffff0000u);
    l = (short)(__float_as_uint(r2) >> 16);
}

static __device__ __forceinline__ void gl_lds16(const void* g, void* l) {
    __builtin_amdgcn_global_load_lds(
        (const __attribute__((address_space(1))) u32*)g,
        (__attribute__((address_space(3))) u32*)l, 16, 0, 0);
}

// ---- kernel 0: slice gate_w into 3 bf16 levels, LDS-lane-ordered image ----
// unit16 U'(c,kk,lv,t,q,m) = c*1536 + (kk*3+lv)*256 + t*64 + q*16 + m,
// holding w[e=t*16+m][k0..k0+7], k0 = c*64 + kk*32 + q*8.  24 KB per c-chunk.
__global__ __launch_bounds__(256)
void w_prep(const float* __restrict__ gw, short* __restrict__ wimg) {
    const int uid = blockIdx.x * 256 + threadIdx.x;   // 8192 threads
    const int c   = uid >> 9;
    const int kk  = (uid >> 8) & 1;
    const int e   = (uid >> 2) & 63;
    const int q   = uid & 3;
    const int k0  = c * 64 + kk * 32 + q * 8;
    const float* src = gw + (size_t)e * DDIM + k0;
    s8 hv, mv, lv;
    #pragma unroll
    for (int j = 0; j < 8; ++j) {
        short h, m, l;
        split3(src[j], h, m, l);
        hv[j] = h; mv[j] = m; lv[j] = l;
    }
    const size_t base = (size_t)c * 1536 + (kk * 3) * 256
                      + (e >> 4) * 64 + q * 16 + (e & 15);
    *(s8*)(wimg + (base      ) * 8) = hv;
    *(s8*)(wimg + (base + 256) * 8) = mv;
    *(s8*)(wimg + (base + 512) * 8) = lv;
}

// ---- kernel 1: split-K MFMA GEMM -> fp32 partials ----
__global__ __launch_bounds__(256, 4)
void gemm_partial(const float* __restrict__ x,
                  const short* __restrict__ wimg,
                  float* __restrict__ part)     // [NSPLIT][NTOK][NEXP]
{
    __shared__ short bs[1536 * 8];              // 24 KB: one k64 B-chunk

    const int tid   = threadIdx.x;
    const int lane  = tid & 63;
    const int wv    = tid >> 6;
    const int m     = lane & 15;                // token row / A-frag m
    const int q     = lane >> 4;                // k-octet quad
    const int tile  = blockIdx.x & 255;
    const int split = blockIdx.x >> 8;
    const int tokBase = tile * 64 + wv * 16;

    const float* xrow = x + (size_t)(tokBase + m) * DDIM
                      + split * (CPB * 64) + q * 8;

    f4 acc0[4], acc1[4];
    #pragma unroll
    for (int t = 0; t < 4; ++t) { acc0[t] = (f4)0.f; acc1[t] = (f4)0.f; }

    // A staging, depth-1 prefetch
    f4 stage[2][4];
    stage[0][0] = *(const f4*)(xrow);
    stage[0][1] = *(const f4*)(xrow + 4);
    stage[0][2] = *(const f4*)(xrow + 32);
    stage[0][3] = *(const f4*)(xrow + 36);

    #pragma unroll
    for (int cc = 0; cc < CPB; ++cc) {
        const short* chunk = wimg + (size_t)(split * CPB + cc) * (1536 * 8);
        __syncthreads();                         // prior reads done
        #pragma unroll
        for (int i = 0; i < 6; ++i) {            // flat async copy, 1KB/wave-iter
            const int off = (wv * 6 + i) * 512;  // shorts
            gl_lds16(chunk + off + lane * 8, &bs[off]);
        }
        __syncthreads();                         // vmcnt(0) drain -> B visible

        if (cc + 1 < CPB) {                      // prefetch next A chunk
            const float* s = xrow + (cc + 1) * 64;
            stage[(cc + 1) & 1][0] = *(const f4*)(s);
            stage[(cc + 1) & 1][1] = *(const f4*)(s + 4);
            stage[(cc + 1) & 1][2] = *(const f4*)(s + 32);
            stage[(cc + 1) & 1][3] = *(const f4*)(s + 36);
        }

        // convert current A chunk -> 3-level bf16 frags
        s8 ah[2], am[2], al[2];
        const float* sv = (const float*)stage[cc & 1];
        #pragma unroll
        for (int kk = 0; kk < 2; ++kk)
            #pragma unroll
            for (int j = 0; j < 8; ++j) {
                short h, mm, l;
                split3(sv[kk * 8 + j], h, mm, l);
                ah[kk][j] = h; am[kk][j] = mm; al[kk][j] = l;
            }

        #pragma unroll
        for (int kk = 0; kk < 2; ++kk) {
            #pragma unroll
            for (int t = 0; t < 4; ++t) {
                const int pb = (kk * 3) * 256 + t * 64 + lane;   // stride-1 across lanes
                const s8 bh = *(const s8*)&bs[(pb      ) * 8];
                const s8 bm = *(const s8*)&bs[(pb + 256) * 8];
                const s8 bl = *(const s8*)&bs[(pb + 512) * 8];
                acc0[t] = __builtin_amdgcn_mfma_f32_16x16x32_bf16(ah[kk], bh, acc0[t], 0, 0, 0);
                acc1[t] = __builtin_amdgcn_mfma_f32_16x16x32_bf16(ah[kk], bm, acc1[t], 0, 0, 0);
                acc1[t] = __builtin_amdgcn_mfma_f32_16x16x32_bf16(am[kk], bh, acc1[t], 0, 0, 0);
                acc1[t] = __builtin_amdgcn_mfma_f32_16x16x32_bf16(ah[kk], bl, acc1[t], 0, 0, 0);
                acc1[t] = __builtin_amdgcn_mfma_f32_16x16x32_bf16(am[kk], bm, acc1[t], 0, 0, 0);
                acc1[t] = __builtin_amdgcn_mfma_f32_16x16x32_bf16(al[kk], bh, acc1[t], 0, 0, 0);
            }
        }
    }

    // store partials: C row = q*4+r (token), col = m (+16t experts)
    #pragma unroll
    for (int t = 0; t < 4; ++t)
        #pragma unroll
        for (int r = 0; r < 4; ++r)
            part[((size_t)split * NTOK + tokBase + q * 4 + r) * NEXP + m + 16 * t]
                = acc0[t][r] + acc1[t][r];
}

// ---- kernel 2: reduce splits + noisy top-2 + sparse softmax (r3-verified) ----
__global__ __launch_bounds__(256)
void reduce_topk(const float* __restrict__ part,
                 const float* __restrict__ noise_weight,
                 const float* __restrict__ noise,
                 float* __restrict__ out_w,
                 float* __restrict__ out_i)
{
    const int lane  = threadIdx.x & 63;          // expert
    const int wv    = threadIdx.x >> 6;
    const int token = blockIdx.x * 4 + wv;

    float sum = 0.f;
    #pragma unroll
    for (int s = 0; s < NSPLIT; ++s)
        sum += part[((size_t)s * NTOK + token) * NEXP + lane];

    const float ln = fmaf(noise[(size_t)token * NEXP + lane], noise_weight[lane], sum);

    float v1 = ln; int i1 = lane;
    #pragma unroll
    for (int off = 32; off > 0; off >>= 1) {
        const float vo = __shfl_xor(v1, off, 64);
        const int   io = __shfl_xor(i1, off, 64);
        if (vo > v1 || (vo == v1 && io < i1)) { v1 = vo; i1 = io; }
    }
    float v2 = (lane == i1) ? -3.4e38f : ln; int i2 = lane;
    #pragma unroll
    for (int off = 32; off > 0; off >>= 1) {
        const float vo = __shfl_xor(v2, off, 64);
        const int   io = __shfl_xor(i2, off, 64);
        if (vo > v2 || (vo == v2 && io < i2)) { v2 = vo; i2 = io; }
    }

    const float d   = expf(v2 - v1);
    const float inv = 1.f / (1.f + d);
    const float wgt = (lane == i1) ? inv : ((lane == i2) ? d * inv : 0.f);
    out_w[(size_t)token * NEXP + lane] = wgt;
    if (lane == 0) {
        out_i[(size_t)token * 2]     = (float)i1;
        out_i[(size_t)token * 2 + 1] = (float)i2;
    }
}

extern "C" void kernel_launch(void* const* d_in, const int* in_sizes, int n_in,
                              void* d_out, int out_size, void* d_ws, size_t ws_size,
                              hipStream_t stream) {
    const float* x     = (const float*)d_in[0];
    const float* gw    = (const float*)d_in[1];
    const float* nwt   = (const float*)d_in[2];
    const float* noise = (const float*)d_in[3];
    float* out_w = (float*)d_out;                        // [NTOK][64]
    float* out_i = (float*)d_out + (size_t)NTOK * NEXP;  // [NTOK][2] as float

    short* wimg = (short*)d_ws;                          // 384 KB image
    float* part = (float*)((char*)d_ws + 512 * 1024);    // 16 MB partials

    hipLaunchKernelGGL(w_prep, dim3(32), dim3(256), 0, stream, gw, wimg);
    hipLaunchKernelGGL(gemm_partial, dim3(256 * NSPLIT), dim3(256), 0, stream,
                       x, wimg, part);
    hipLaunchKernelGGL(reduce_topk, dim3(NTOK / 4), dim3(256), 0, stream,
                       part, nwt, noise, out_w, out_i);
}